// Round 8
// baseline (412.750 us; speedup 1.0000x reference)
//
#include <hip/hip_runtime.h>

#define HID 32
#define SEQ 512
#define WAVES_PER_BLOCK 4
#define BLOCK (WAVES_PER_BLOCK * 64)

typedef float v2f __attribute__((ext_vector_type(2)));

// ---------------------------------------------------------------------------
// ONE WAVE = ONE BATCH SAMPLE; whole 32-step inner loop is one asm block
// (round 7, kept). Round-7 counters showed the binding pipe was LDS: 12 DS
// ops/step/wave x 16 waves/CU ~= the entire 1481-cycle wall re-broadcasting
// h through the 256 B/clk LDS return path. This round replaces the LDS
// h/x round-trip with v_readlane -> SGPR (VALU pipe) + v_pk_fma_f32 reading
// the SGPR pair directly via the validated op_sel splat forms. DS ops/step:
// 12 -> 2 (only the cross-half bpermute exchange survives, unchanged from
// round 7 => bitwise-identical dataflow; half1 remains a garbage-half, the
// authoritative h lives in lanes 0..31 which is all readlane touches).
//
// Lane roles: lane=(half,k). half0 owns gates (i,f) of unit k, half1 (g,o).
// ---------------------------------------------------------------------------

// acc += wE*h_even + wO*h_odd, h from SGPR pair SP (s[40+2m:41+2m]):
//   op_sel_hi:[1,0,1]                -> both halves multiply by SP.lo
//   op_sel:[0,1,0] op_sel_hi:[1,1,1] -> both halves multiply by SP.hi
#define PKS(WE, WO, SP) \
  "v_pk_fma_f32 v[80:81], %[" WE "], s[" SP "], v[80:81] op_sel_hi:[1,0,1]\n\t" \
  "v_pk_fma_f32 v[80:81], %[" WO "], s[" SP "], v[80:81] op_sel:[0,1,0] op_sel_hi:[1,1,1]\n\t"

// 32 h-broadcast readlanes: s(40+j) = h[j] (lanes 0..31 hold true h).
#define RLH \
  "v_readlane_b32 s40, %[h], 0\n\t"  "v_readlane_b32 s41, %[h], 1\n\t" \
  "v_readlane_b32 s42, %[h], 2\n\t"  "v_readlane_b32 s43, %[h], 3\n\t" \
  "v_readlane_b32 s44, %[h], 4\n\t"  "v_readlane_b32 s45, %[h], 5\n\t" \
  "v_readlane_b32 s46, %[h], 6\n\t"  "v_readlane_b32 s47, %[h], 7\n\t" \
  "v_readlane_b32 s48, %[h], 8\n\t"  "v_readlane_b32 s49, %[h], 9\n\t" \
  "v_readlane_b32 s50, %[h], 10\n\t" "v_readlane_b32 s51, %[h], 11\n\t" \
  "v_readlane_b32 s52, %[h], 12\n\t" "v_readlane_b32 s53, %[h], 13\n\t" \
  "v_readlane_b32 s54, %[h], 14\n\t" "v_readlane_b32 s55, %[h], 15\n\t" \
  "v_readlane_b32 s56, %[h], 16\n\t" "v_readlane_b32 s57, %[h], 17\n\t" \
  "v_readlane_b32 s58, %[h], 18\n\t" "v_readlane_b32 s59, %[h], 19\n\t" \
  "v_readlane_b32 s60, %[h], 20\n\t" "v_readlane_b32 s61, %[h], 21\n\t" \
  "v_readlane_b32 s62, %[h], 22\n\t" "v_readlane_b32 s63, %[h], 23\n\t" \
  "v_readlane_b32 s64, %[h], 24\n\t" "v_readlane_b32 s65, %[h], 25\n\t" \
  "v_readlane_b32 s66, %[h], 26\n\t" "v_readlane_b32 s67, %[h], 27\n\t" \
  "v_readlane_b32 s68, %[h], 28\n\t" "v_readlane_b32 s69, %[h], 29\n\t" \
  "v_readlane_b32 s70, %[h], 30\n\t" "v_readlane_b32 s71, %[h], 31\n\t"

// One timestep. Scratch: v[80:81]=acc, v84-v90 activation temps.
// Activation formulas and the bpermute exchange are byte-for-byte round 7's
// (absmax 0.0): half0 x-comp sigma(pi), half1 tanh(pg) via per-lane affine;
// y-comp sigma for both; partner values fetched with ds_bpermute lane^32.
#define STEPSTR(TT) \
  "s_nop 0\n\t" \
  "v_readlane_b32 s38, %[xv], " TT "\n\t" \
  RLH \
  "v_pk_fma_f32 v[80:81], %[uv], s[38:39], %[bv] op_sel_hi:[1,0,1]\n\t" \
  PKS("w0","w1","40:41")   PKS("w2","w3","42:43") \
  PKS("w4","w5","44:45")   PKS("w6","w7","46:47") \
  PKS("w8","w9","48:49")   PKS("w10","w11","50:51") \
  PKS("w12","w13","52:53") PKS("w14","w15","54:55") \
  PKS("w16","w17","56:57") PKS("w18","w19","58:59") \
  PKS("w20","w21","60:61") PKS("w22","w23","62:63") \
  PKS("w24","w25","64:65") PKS("w26","w27","66:67") \
  PKS("w28","w29","68:69") PKS("w30","w31","70:71") \
  "v_mul_f32 v84, %[vSX], v80\n\t" \
  "v_mul_f32 v85, 0xbfb8aa3b, v81\n\t" \
  "v_exp_f32 v84, v84\n\t" \
  "v_exp_f32 v85, v85\n\t" \
  "s_nop 1\n\t" \
  "v_add_f32 v84, 1.0, v84\n\t" \
  "v_add_f32 v85, 1.0, v85\n\t" \
  "v_rcp_f32 v84, v84\n\t" \
  "v_rcp_f32 v85, v85\n\t" \
  "s_nop 1\n\t" \
  "v_fma_f32 v86, %[vB], v84, %[vA]\n\t" \
  "ds_bpermute_b32 v87, %[vXOR], v86\n\t" \
  "ds_bpermute_b32 v88, %[vXOR], v85\n\t" \
  "s_waitcnt lgkmcnt(0)\n\t" \
  "v_mul_f32 v89, v86, v87\n\t" \
  "v_fma_f32 %[c], v85, %[c], v89\n\t" \
  "v_mul_f32 v90, 0x4038aa3b, %[c]\n\t" \
  "v_exp_f32 v90, v90\n\t" \
  "s_nop 1\n\t" \
  "v_add_f32 v90, 1.0, v90\n\t" \
  "v_rcp_f32 v90, v90\n\t" \
  "s_nop 1\n\t" \
  "v_fma_f32 v90, -2.0, v90, 1.0\n\t" \
  "v_mul_f32 %[h], v88, v90\n\t"

#define X32 \
  STEPSTR("0")  STEPSTR("1")  STEPSTR("2")  STEPSTR("3") \
  STEPSTR("4")  STEPSTR("5")  STEPSTR("6")  STEPSTR("7") \
  STEPSTR("8")  STEPSTR("9")  STEPSTR("10") STEPSTR("11") \
  STEPSTR("12") STEPSTR("13") STEPSTR("14") STEPSTR("15") \
  STEPSTR("16") STEPSTR("17") STEPSTR("18") STEPSTR("19") \
  STEPSTR("20") STEPSTR("21") STEPSTR("22") STEPSTR("23") \
  STEPSTR("24") STEPSTR("25") STEPSTR("26") STEPSTR("27") \
  STEPSTR("28") STEPSTR("29") STEPSTR("30") STEPSTR("31")

__global__ __launch_bounds__(BLOCK)
void lstm_fused_kernel(
    const float* __restrict__ x,       // [B, T, 1]
    const float* __restrict__ W_ih,    // [4H, 1]
    const float* __restrict__ W_hh,    // [4H, H] row-major
    const float* __restrict__ b_ih,    // [4H]
    const float* __restrict__ b_hh,    // [4H]
    const float* __restrict__ W_head,  // [1, H]
    const float* __restrict__ b_head,  // [1]
    float* __restrict__ out)           // [B, 1]
{
    // WL[j*64 + lane] = (W_hh[rowA][j], W_hh[rowA+32][j]),
    // rowA = half*64 + k  (half0: i/f rows; half1: g/o rows).
    __shared__ v2f WL[32 * 64];                                  // 16 KB

    const int tid = threadIdx.x;
    for (int idx = tid; idx < 32 * 64; idx += BLOCK) {
        const int j    = idx >> 6;
        const int l    = idx & 63;
        const int rowA = ((l >> 5) << 6) + (l & 31);
        WL[idx] = (v2f){ W_hh[rowA * 32 + j], W_hh[(rowA + 32) * 32 + j] };
    }
    __syncthreads();

    const int  lane = tid & 63;
    const int  k    = lane & 31;
    const bool hi   = lane >= 32;
    const int  wid  = tid >> 6;
    const int  b    = blockIdx.x * WAVES_PER_BLOCK + wid;

    // 32 weight pairs per lane; bound once per asm entry (16 entries total).
    v2f w[HID];
#pragma unroll
    for (int j = 0; j < HID; ++j) w[j] = WL[j * 64 + lane];

    const int gA = (hi ? 64 : 0) + k;   // i-row (half0) or g-row (half1)
    const int gB = gA + 32;             // f-row or o-row
    const v2f bv = { b_ih[gA] + b_hh[gA], b_ih[gB] + b_hh[gB] };
    const v2f uv = { W_ih[gA], W_ih[gB] };

    const unsigned vXOR = (unsigned)(((lane ^ 32) & 63) * 4);  // bpermute addr
    // x-activation: e = exp2(sX*p); r = rcp(1+e); result = B*r + A.
    // half0: sigma (sX=-log2e, A=0, B=1); half1: tanh (sX=+2log2e, A=1, B=-2).
    const float vSX = hi ?  2.8853900817779268f : -1.4426950408889634f;
    const float vA  = hi ?  1.0f :  0.0f;
    const float vB  = hi ? -2.0f :  1.0f;

    const float* xb = x + (size_t)b * SEQ;   // I == 1

    float h = 0.0f, c = 0.0f;

#pragma unroll 1
    for (int t0 = 0; t0 < SEQ; t0 += 32) {
        const float xv = xb[t0 + k];   // lane k prefetches x[b][t0+k]
        asm volatile(
            X32
            : [h]"+v"(h), [c]"+v"(c)
            : [w0]"v"(w[0]),  [w1]"v"(w[1]),  [w2]"v"(w[2]),  [w3]"v"(w[3]),
              [w4]"v"(w[4]),  [w5]"v"(w[5]),  [w6]"v"(w[6]),  [w7]"v"(w[7]),
              [w8]"v"(w[8]),  [w9]"v"(w[9]),  [w10]"v"(w[10]),[w11]"v"(w[11]),
              [w12]"v"(w[12]),[w13]"v"(w[13]),[w14]"v"(w[14]),[w15]"v"(w[15]),
              [w16]"v"(w[16]),[w17]"v"(w[17]),[w18]"v"(w[18]),[w19]"v"(w[19]),
              [w20]"v"(w[20]),[w21]"v"(w[21]),[w22]"v"(w[22]),[w23]"v"(w[23]),
              [w24]"v"(w[24]),[w25]"v"(w[25]),[w26]"v"(w[26]),[w27]"v"(w[27]),
              [w28]"v"(w[28]),[w29]"v"(w[29]),[w30]"v"(w[30]),[w31]"v"(w[31]),
              [uv]"v"(uv), [bv]"v"(bv), [xv]"v"(xv), [vXOR]"v"(vXOR),
              [vSX]"v"(vSX), [vA]"v"(vA), [vB]"v"(vB)
            : "v80","v81","v84","v85","v86","v87","v88","v89","v90",
              "s38","s40","s41","s42","s43","s44","s45","s46","s47",
              "s48","s49","s50","s51","s52","s53","s54","s55","s56","s57",
              "s58","s59","s60","s61","s62","s63","s64","s65","s66","s67",
              "s68","s69","s70","s71");
    }

    // half1's h is garbage (round-7 design); lanes 0..31 hold the truth and
    // the width-32 reduce stays inside half0. lane 0 writes.
    float v = h * W_head[k];
#pragma unroll
    for (int off = 16; off >= 1; off >>= 1)
        v += __shfl_xor(v, off, 32);
    if (lane == 0) out[b] = v + b_head[0];
}

extern "C" void kernel_launch(void* const* d_in, const int* in_sizes, int n_in,
                              void* d_out, int out_size, void* d_ws, size_t ws_size,
                              hipStream_t stream) {
    const float* x      = (const float*)d_in[0];
    const float* W_ih   = (const float*)d_in[1];
    const float* W_hh   = (const float*)d_in[2];
    const float* b_ih   = (const float*)d_in[3];
    const float* b_hh   = (const float*)d_in[4];
    const float* W_head = (const float*)d_in[5];
    const float* b_head = (const float*)d_in[6];
    float* out = (float*)d_out;

    const int B = in_sizes[0] / SEQ;              // 4096
    const int grid = B / WAVES_PER_BLOCK;         // 1024 blocks (4 waves each)

    lstm_fused_kernel<<<grid, BLOCK, 0, stream>>>(
        x, W_ih, W_hh, b_ih, b_hh, W_head, b_head, out);
}

// Round 9
// 295.121 us; speedup vs baseline: 1.3986x; 1.3986x over previous
//
#include <hip/hip_runtime.h>

#define HID 32
#define SEQ 512
#define WAVES_PER_BLOCK 4
#define BLOCK (WAVES_PER_BLOCK * 64)

typedef float v2f __attribute__((ext_vector_type(2)));

// ---------------------------------------------------------------------------
// ONE WAVE = TWO SAMPLES; lane (s,k) = sample s (lane>>5), unit k (lane&31),
// owning ALL FOUR gates of its unit -> no cross-lane exchange at all.
// 128 weight floats/lane live in persistent hard-coded regs v96..v223,
// loaded ONCE by a preload asm block; every asm block clobbers v64..v223 so
// the compiler never allocates there and the values persist across blocks.
// DS per step per wave: 1 read2(x) + 8 b128(h, 2-address broadcast) +
// 1 write(h) = 10; at 8 waves/CU that is 80 DS/CU-step vs round-7's 192 --
// the measured binder. All gate-chain and activation arithmetic is
// byte-identical to rounds 6-8 (absmax 0.0 each time).
// Register map: v64..79 h-quads (4-slot pipeline) | v80:81 accIF (pi,pf) |
// v82:83 accGO (pg,po) | v84:85 (xt,xt) | v86..92 activation temps |
// v96+2j (wi,wf)[j] | v160+2j (wg,wo)[j].
// ---------------------------------------------------------------------------

// acc{IF,GO} += pair_j * h[j] ; h-pair HP feeds two j's via validated op_sel:
//   op_sel_hi:[1,0,1]                -> both gate-halves multiply by HP.lo
//   op_sel:[0,1,0] op_sel_hi:[1,1,1] -> both gate-halves multiply by HP.hi
#define PKP(IFE, IFO, GOE, GOO, HP) \
  "v_pk_fma_f32 v[80:81], v[" IFE "], v[" HP "], v[80:81] op_sel_hi:[1,0,1]\n\t" \
  "v_pk_fma_f32 v[82:83], v[" GOE "], v[" HP "], v[82:83] op_sel_hi:[1,0,1]\n\t" \
  "v_pk_fma_f32 v[80:81], v[" IFO "], v[" HP "], v[80:81] op_sel:[0,1,0] op_sel_hi:[1,1,1]\n\t" \
  "v_pk_fma_f32 v[82:83], v[" GOO "], v[" HP "], v[82:83] op_sel:[0,1,0] op_sel_hi:[1,1,1]\n\t"

// One timestep; TT = step index (string, 0..31). lgkmcnt accounting: stale
// prior ops (h-write / C's x-write) only make the waits stricter (LDS is
// in-order per wave), never looser.
#define STEP(TT) \
  "ds_read2_b32 v[84:85], %[xa] offset0:" TT " offset1:" TT "\n\t" \
  "ds_read_b128 v[64:67], %[hr] offset:0\n\t" \
  "ds_read_b128 v[68:71], %[hr] offset:16\n\t" \
  "ds_read_b128 v[72:75], %[hr] offset:32\n\t" \
  "ds_read_b128 v[76:79], %[hr] offset:48\n\t" \
  "s_waitcnt lgkmcnt(4)\n\t" \
  "v_pk_fma_f32 v[80:81], %[uvIF], v[84:85], %[bvIF]\n\t" \
  "v_pk_fma_f32 v[82:83], %[uvGO], v[84:85], %[bvGO]\n\t" \
  "s_waitcnt lgkmcnt(3)\n\t" \
  PKP("96:97","98:99","160:161","162:163","64:65") \
  PKP("100:101","102:103","164:165","166:167","66:67") \
  "ds_read_b128 v[64:67], %[hr] offset:64\n\t" \
  "s_waitcnt lgkmcnt(3)\n\t" \
  PKP("104:105","106:107","168:169","170:171","68:69") \
  PKP("108:109","110:111","172:173","174:175","70:71") \
  "ds_read_b128 v[68:71], %[hr] offset:80\n\t" \
  "s_waitcnt lgkmcnt(3)\n\t" \
  PKP("112:113","114:115","176:177","178:179","72:73") \
  PKP("116:117","118:119","180:181","182:183","74:75") \
  "ds_read_b128 v[72:75], %[hr] offset:96\n\t" \
  "s_waitcnt lgkmcnt(3)\n\t" \
  PKP("120:121","122:123","184:185","186:187","76:77") \
  PKP("124:125","126:127","188:189","190:191","78:79") \
  "ds_read_b128 v[76:79], %[hr] offset:112\n\t" \
  "s_waitcnt lgkmcnt(3)\n\t" \
  PKP("128:129","130:131","192:193","194:195","64:65") \
  PKP("132:133","134:135","196:197","198:199","66:67") \
  "s_waitcnt lgkmcnt(2)\n\t" \
  PKP("136:137","138:139","200:201","202:203","68:69") \
  PKP("140:141","142:143","204:205","206:207","70:71") \
  "s_waitcnt lgkmcnt(1)\n\t" \
  PKP("144:145","146:147","208:209","210:211","72:73") \
  PKP("148:149","150:151","212:213","214:215","74:75") \
  "s_waitcnt lgkmcnt(0)\n\t" \
  PKP("152:153","154:155","216:217","218:219","76:77") \
  PKP("156:157","158:159","220:221","222:223","78:79") \
  "v_mul_f32 v86, 0xbfb8aa3b, v80\n\t" \
  "v_mul_f32 v87, 0xbfb8aa3b, v81\n\t" \
  "v_mul_f32 v88, 0x4038aa3b, v82\n\t" \
  "v_mul_f32 v89, 0xbfb8aa3b, v83\n\t" \
  "v_exp_f32 v86, v86\n\t" \
  "v_exp_f32 v87, v87\n\t" \
  "v_exp_f32 v88, v88\n\t" \
  "v_exp_f32 v89, v89\n\t" \
  "v_add_f32 v86, 1.0, v86\n\t" \
  "v_add_f32 v87, 1.0, v87\n\t" \
  "v_add_f32 v88, 1.0, v88\n\t" \
  "v_add_f32 v89, 1.0, v89\n\t" \
  "v_rcp_f32 v86, v86\n\t" \
  "v_rcp_f32 v87, v87\n\t" \
  "v_rcp_f32 v88, v88\n\t" \
  "v_rcp_f32 v89, v89\n\t" \
  "s_nop 1\n\t" \
  "v_fma_f32 v90, -2.0, v88, 1.0\n\t" \
  "v_mul_f32 v91, v86, v90\n\t" \
  "v_fma_f32 %[c], v87, %[c], v91\n\t" \
  "v_mul_f32 v92, 0x4038aa3b, %[c]\n\t" \
  "v_exp_f32 v92, v92\n\t" \
  "s_nop 1\n\t" \
  "v_add_f32 v92, 1.0, v92\n\t" \
  "v_rcp_f32 v92, v92\n\t" \
  "s_nop 1\n\t" \
  "v_fma_f32 v92, -2.0, v92, 1.0\n\t" \
  "v_mul_f32 %[h], v89, v92\n\t" \
  "ds_write_b32 %[hw], %[h]\n\t"

#define CLOBS \
  "v64","v65","v66","v67","v68","v69","v70","v71","v72","v73","v74","v75", \
  "v76","v77","v78","v79","v80","v81","v82","v83","v84","v85","v86","v87", \
  "v88","v89","v90","v91","v92","v93","v94","v95","v96","v97","v98","v99", \
  "v100","v101","v102","v103","v104","v105","v106","v107","v108","v109", \
  "v110","v111","v112","v113","v114","v115","v116","v117","v118","v119", \
  "v120","v121","v122","v123","v124","v125","v126","v127","v128","v129", \
  "v130","v131","v132","v133","v134","v135","v136","v137","v138","v139", \
  "v140","v141","v142","v143","v144","v145","v146","v147","v148","v149", \
  "v150","v151","v152","v153","v154","v155","v156","v157","v158","v159", \
  "v160","v161","v162","v163","v164","v165","v166","v167","v168","v169", \
  "v170","v171","v172","v173","v174","v175","v176","v177","v178","v179", \
  "v180","v181","v182","v183","v184","v185","v186","v187","v188","v189", \
  "v190","v191","v192","v193","v194","v195","v196","v197","v198","v199", \
  "v200","v201","v202","v203","v204","v205","v206","v207","v208","v209", \
  "v210","v211","v212","v213","v214","v215","v216","v217","v218","v219", \
  "v220","v221","v222","v223"

__global__ __launch_bounds__(BLOCK)
void lstm_fused_kernel(
    const float* __restrict__ x,       // [B, T, 1]
    const float* __restrict__ W_ih,    // [4H, 1]
    const float* __restrict__ W_hh,    // [4H, H] row-major
    const float* __restrict__ b_ih,    // [4H]
    const float* __restrict__ b_hh,    // [4H]
    const float* __restrict__ W_head,  // [1, H]
    const float* __restrict__ b_head,  // [1]
    float* __restrict__ out)           // [B, 1]
{
    // Per-unit contiguous pair rows (row stride 34 pairs = 272 B: 16B-aligned
    // for b128, bank-spread). WIFL[u][j]=(wi,wf); WGOL[u][j]=(wg,wo).
    __shared__ __align__(16) v2f WIFL[32][34];
    __shared__ __align__(16) v2f WGOL[32][34];
    __shared__ __align__(16) float Hbuf[WAVES_PER_BLOCK][2][32];
    __shared__ __align__(16) float Xbuf[WAVES_PER_BLOCK][2][32];

    const int tid = threadIdx.x;
    for (int idx = tid; idx < 1024; idx += BLOCK) {
        const int u = idx >> 5;
        const int j = idx & 31;
        WIFL[u][j] = (v2f){ W_hh[u * 32 + j],        W_hh[(32 + u) * 32 + j] };
        WGOL[u][j] = (v2f){ W_hh[(64 + u) * 32 + j], W_hh[(96 + u) * 32 + j] };
    }
    __syncthreads();

    const int lane = tid & 63;
    const int u    = lane & 31;   // unit owned by this lane
    const int s    = lane >> 5;   // which of the wave's two samples
    const int wid  = tid >> 6;
    const int b0   = 2 * (blockIdx.x * WAVES_PER_BLOCK + wid);

    // Preload all 64 weight pairs into persistent regs v96..v223 (once).
    {
        const unsigned aIF = (unsigned)(size_t)&WIFL[u][0];
        const unsigned aGO = (unsigned)(size_t)&WGOL[u][0];
        asm volatile(
            "ds_read_b128 v[96:99],   %[wa] offset:0\n\t"
            "ds_read_b128 v[100:103], %[wa] offset:16\n\t"
            "ds_read_b128 v[104:107], %[wa] offset:32\n\t"
            "ds_read_b128 v[108:111], %[wa] offset:48\n\t"
            "ds_read_b128 v[112:115], %[wa] offset:64\n\t"
            "ds_read_b128 v[116:119], %[wa] offset:80\n\t"
            "ds_read_b128 v[120:123], %[wa] offset:96\n\t"
            "ds_read_b128 v[124:127], %[wa] offset:112\n\t"
            "ds_read_b128 v[128:131], %[wa] offset:128\n\t"
            "ds_read_b128 v[132:135], %[wa] offset:144\n\t"
            "ds_read_b128 v[136:139], %[wa] offset:160\n\t"
            "ds_read_b128 v[140:143], %[wa] offset:176\n\t"
            "ds_read_b128 v[144:147], %[wa] offset:192\n\t"
            "ds_read_b128 v[148:151], %[wa] offset:208\n\t"
            "ds_read_b128 v[152:155], %[wa] offset:224\n\t"
            "ds_read_b128 v[156:159], %[wa] offset:240\n\t"
            "ds_read_b128 v[160:163], %[wb] offset:0\n\t"
            "ds_read_b128 v[164:167], %[wb] offset:16\n\t"
            "ds_read_b128 v[168:171], %[wb] offset:32\n\t"
            "ds_read_b128 v[172:175], %[wb] offset:48\n\t"
            "ds_read_b128 v[176:179], %[wb] offset:64\n\t"
            "ds_read_b128 v[180:183], %[wb] offset:80\n\t"
            "ds_read_b128 v[184:187], %[wb] offset:96\n\t"
            "ds_read_b128 v[188:191], %[wb] offset:112\n\t"
            "ds_read_b128 v[192:195], %[wb] offset:128\n\t"
            "ds_read_b128 v[196:199], %[wb] offset:144\n\t"
            "ds_read_b128 v[200:203], %[wb] offset:160\n\t"
            "ds_read_b128 v[204:207], %[wb] offset:176\n\t"
            "ds_read_b128 v[208:211], %[wb] offset:192\n\t"
            "ds_read_b128 v[212:215], %[wb] offset:208\n\t"
            "ds_read_b128 v[216:219], %[wb] offset:224\n\t"
            "ds_read_b128 v[220:223], %[wb] offset:240\n\t"
            "s_waitcnt lgkmcnt(0)"
            :
            : [wa]"v"(aIF), [wb]"v"(aGO)
            : "memory", CLOBS);
    }

    const v2f bvIF = { b_ih[u]      + b_hh[u],      b_ih[32 + u] + b_hh[32 + u] };
    const v2f bvGO = { b_ih[64 + u] + b_hh[64 + u], b_ih[96 + u] + b_hh[96 + u] };
    const v2f uvIF = { W_ih[u],      W_ih[32 + u] };
    const v2f uvGO = { W_ih[64 + u], W_ih[96 + u] };

    const unsigned hr = (unsigned)(size_t)&Hbuf[wid][s][0];   // uniform per half
    const unsigned hw = hr + (unsigned)(u * 4);               // own h slot
    const unsigned xa = (unsigned)(size_t)&Xbuf[wid][s][0];   // uniform per half

    const float* xb = x + (size_t)(b0 + s) * SEQ;   // this lane's sample, I==1

    float h = 0.0f, c = 0.0f;
    Hbuf[wid][s][u] = 0.0f;   // h(0); same-wave LDS is in-order -> visible

#pragma unroll 1
    for (int t0 = 0; t0 < SEQ; t0 += 32) {
        Xbuf[wid][s][u] = xb[t0 + u];   // stage 32 timesteps of x for sample s
        asm volatile(
            STEP("0")  STEP("1")  STEP("2")  STEP("3")
            STEP("4")  STEP("5")  STEP("6")  STEP("7")
            STEP("8")  STEP("9")  STEP("10") STEP("11")
            STEP("12") STEP("13") STEP("14") STEP("15")
            STEP("16") STEP("17") STEP("18") STEP("19")
            STEP("20") STEP("21") STEP("22") STEP("23")
            STEP("24") STEP("25") STEP("26") STEP("27")
            STEP("28") STEP("29") STEP("30") STEP("31")
            : [h]"+v"(h), [c]"+v"(c)
            : [hr]"v"(hr), [hw]"v"(hw), [xa]"v"(xa),
              [uvIF]"v"(uvIF), [bvIF]"v"(bvIF),
              [uvGO]"v"(uvGO), [bvGO]"v"(bvGO)
            : "memory", CLOBS);
    }

    // head: out[b0+s] = sum_u h[u]*W_head[u] + b_head. xor offsets <32 keep
    // the reduction inside each 32-lane half (per sample).
    float v = h * W_head[u];
#pragma unroll
    for (int off = 16; off >= 1; off >>= 1)
        v += __shfl_xor(v, off);
    if (u == 0) out[b0 + s] = v + b_head[0];
}

extern "C" void kernel_launch(void* const* d_in, const int* in_sizes, int n_in,
                              void* d_out, int out_size, void* d_ws, size_t ws_size,
                              hipStream_t stream) {
    const float* x      = (const float*)d_in[0];
    const float* W_ih   = (const float*)d_in[1];
    const float* W_hh   = (const float*)d_in[2];
    const float* b_ih   = (const float*)d_in[3];
    const float* b_hh   = (const float*)d_in[4];
    const float* W_head = (const float*)d_in[5];
    const float* b_head = (const float*)d_in[6];
    float* out = (float*)d_out;

    const int B = in_sizes[0] / SEQ;                    // 4096
    const int grid = B / (2 * WAVES_PER_BLOCK);         // 512 blocks

    lstm_fused_kernel<<<grid, BLOCK, 0, stream>>>(
        x, W_ih, W_hh, b_ih, b_hh, W_head, b_head, out);
}